// Round 1
// baseline (280.830 us; speedup 1.0000x reference)
//
#include <hip/hip_runtime.h>

#define NTOK 262144L
#define DIN 512
#define HID 128

typedef __attribute__((ext_vector_type(4))) float f32x4;
typedef __attribute__((ext_vector_type(8))) short bf16x8;   // 8 x bf16 (4 VGPRs)

static __device__ __forceinline__ unsigned short f2bf(float f) {
  unsigned int u = __builtin_bit_cast(unsigned int, f);
  u += 0x7fffu + ((u >> 16) & 1u);          // round-nearest-even (inputs are normal)
  return (unsigned short)(u >> 16);
}

// ---- pre-pack all weights fp32 -> bf16 in MFMA B-fragment order ----
// W1 region: [e][kt=16][ct=8][lane=64][j=8]  (k = kt*32 + (lane>>4)*8 + j, col = ct*16 + (lane&15))
// W2 region: [e][kt=4 ][ct=8][lane=64][j=8]
__global__ void pack_w(const float* __restrict__ Wt1, const float* __restrict__ Wa1,
                       const float* __restrict__ Wv1, const float* __restrict__ Wt2,
                       const float* __restrict__ Wa2, const float* __restrict__ Wv2,
                       unsigned short* __restrict__ pk) {
  int idx = blockIdx.x * 256 + threadIdx.x;
  if (idx >= 245760) return;
  float v;
  if (idx < 196608) {
    int j = idx & 7, l = (idx >> 3) & 63, ct = (idx >> 9) & 7, kt = (idx >> 12) & 15, e = idx >> 16;
    const float* W = (e == 0) ? Wt1 : (e == 1) ? Wa1 : Wv1;
    v = W[(kt * 32 + ((l >> 4) * 8) + j) * HID + ct * 16 + (l & 15)];
  } else {
    int i2 = idx - 196608;
    int j = i2 & 7, l = (i2 >> 3) & 63, ct = (i2 >> 9) & 7, kt = (i2 >> 12) & 3, e = i2 >> 14;
    const float* W = (e == 0) ? Wt2 : (e == 1) ? Wa2 : Wv2;
    v = W[(kt * 32 + ((l >> 4) * 8) + j) * HID + ct * 16 + (l & 15)];
  }
  pk[idx] = f2bf(v);
}

// MODE 0: transform expert -> keep result in registers (no store)
// MODE 1: actor expert     -> per-row select vs keep[], dense store to pi
// MODE 2: value head       -> outer relu, dense store to vf
template <int MODE>
static __device__ __forceinline__ void expert_pass(
    const unsigned short* Xs, unsigned short* Hs,
    const unsigned short* __restrict__ W1f, const unsigned short* __restrict__ W2f,
    const float* __restrict__ b1, const float* __restrict__ b2,
    float* __restrict__ ob, long brow,
    int lane, int l15, int g, int w, const unsigned short* flg,
    f32x4 keep[4][2])
{
  const int cb = 2 * w;   // this wave's column-tile base (wave owns cols cb*16 .. cb*16+31)

  // ---- layer 1: acc = X @ W1 + b1 ----
  f32x4 acc[4][2];
  #pragma unroll
  for (int c = 0; c < 2; ++c) {
    float bv = b1[(cb + c) * 16 + l15];
    #pragma unroll
    for (int rt = 0; rt < 4; ++rt) {
      acc[rt][c][0] = bv; acc[rt][c][1] = bv; acc[rt][c][2] = bv; acc[rt][c][3] = bv;
    }
  }
  #pragma unroll
  for (int kt = 0; kt < 16; ++kt) {
    bf16x8 bA = *(const bf16x8*)(W1f + ((kt * 8 + cb) << 9) + (lane << 3));
    bf16x8 bB = *(const bf16x8*)(W1f + ((kt * 8 + cb + 1) << 9) + (lane << 3));
    #pragma unroll
    for (int rt = 0; rt < 4; ++rt) {
      int row = rt * 16 + l15;
      bf16x8 a = *(const bf16x8*)((const char*)Xs +
                   ((row * 1024 + kt * 64 + g * 16) ^ ((row & 7) << 4)));
      acc[rt][0] = __builtin_amdgcn_mfma_f32_16x16x32_bf16(a, bA, acc[rt][0], 0, 0, 0);
      acc[rt][1] = __builtin_amdgcn_mfma_f32_16x16x32_bf16(a, bB, acc[rt][1], 0, 0, 0);
    }
  }

  // previous expert's phase-2 reads of Hs are complete once everyone is here
  __syncthreads();

  // ---- relu + write hidden (bf16, swizzled) ----
  #pragma unroll
  for (int rt = 0; rt < 4; ++rt)
    #pragma unroll
    for (int c = 0; c < 2; ++c)
      #pragma unroll
      for (int r = 0; r < 4; ++r) {
        int row = rt * 16 + 4 * g + r;
        int col = (cb + c) * 16 + l15;
        int ha = (row * 256 + col * 2) ^ ((row & 7) << 4);
        *(unsigned short*)((char*)Hs + ha) = f2bf(fmaxf(acc[rt][c][r], 0.f));
      }
  __syncthreads();

  // ---- layer 2: a2 = H @ W2 + b2 ----
  f32x4 a2[4][2];
  #pragma unroll
  for (int c = 0; c < 2; ++c) {
    float bv = b2[(cb + c) * 16 + l15];
    #pragma unroll
    for (int rt = 0; rt < 4; ++rt) {
      a2[rt][c][0] = bv; a2[rt][c][1] = bv; a2[rt][c][2] = bv; a2[rt][c][3] = bv;
    }
  }
  #pragma unroll
  for (int kt = 0; kt < 4; ++kt) {
    bf16x8 bA = *(const bf16x8*)(W2f + ((kt * 8 + cb) << 9) + (lane << 3));
    bf16x8 bB = *(const bf16x8*)(W2f + ((kt * 8 + cb + 1) << 9) + (lane << 3));
    #pragma unroll
    for (int rt = 0; rt < 4; ++rt) {
      int row = rt * 16 + l15;
      bf16x8 a = *(const bf16x8*)((const char*)Hs +
                   ((row * 256 + kt * 64 + g * 16) ^ ((row & 7) << 4)));
      a2[rt][0] = __builtin_amdgcn_mfma_f32_16x16x32_bf16(a, bA, a2[rt][0], 0, 0, 0);
      a2[rt][1] = __builtin_amdgcn_mfma_f32_16x16x32_bf16(a, bB, a2[rt][1], 0, 0, 0);
    }
  }

  // ---- epilogue ----
  #pragma unroll
  for (int rt = 0; rt < 4; ++rt)
    #pragma unroll
    for (int c = 0; c < 2; ++c)
      #pragma unroll
      for (int r = 0; r < 4; ++r) {
        float v = a2[rt][c][r];
        if (MODE == 0) {
          keep[rt][c][r] = v;
        } else {
          long row = brow + rt * 16 + 4 * g + r;
          long col = (cb + c) * 16 + l15;
          if (MODE == 1) {
            float sel = (flg[rt * 4 + r] == 0) ? keep[rt][c][r] : v;  // flag==0 -> transform
            ob[row * 128 + col] = sel;
          } else {
            ob[row * 128 + col] = fmaxf(v, 0.f);
          }
        }
      }
}

__global__ __launch_bounds__(256, 2) void mlp3(
    const float* __restrict__ X, const unsigned short* __restrict__ pk,
    const float* __restrict__ bt1, const float* __restrict__ bt2,
    const float* __restrict__ ba1, const float* __restrict__ ba2,
    const float* __restrict__ bv1, const float* __restrict__ bv2,
    float* __restrict__ out) {
  __shared__ unsigned short Xs[64 * 512];   // 64 KiB, XOR-swizzled bf16 feature tile
  __shared__ unsigned short Hs[64 * 128];   // 16 KiB, swizzled bf16 hidden tile
  const int t = threadIdx.x;
  const long brow = (long)blockIdx.x * 64;

  // ---- stage 64x512 fp32 tile -> bf16 LDS (coalesced float4 sweep) ----
  const float4* Xv = (const float4*)(X + brow * DIN);
  #pragma unroll
  for (int i = 0; i < 32; ++i) {
    int f = t + i * 256;
    int row = f >> 7, c4 = f & 127;
    float4 v = Xv[f];
    unsigned long long p = (unsigned long long)f2bf(v.x)
                         | ((unsigned long long)f2bf(v.y) << 16)
                         | ((unsigned long long)f2bf(v.z) << 32)
                         | ((unsigned long long)f2bf(v.w) << 48);
    int addr = (row * 1024 + c4 * 8) ^ ((row & 7) << 4);
    *(unsigned long long*)((char*)Xs + addr) = p;
  }
  __syncthreads();

  const int lane = t & 63;
  const int w = t >> 6;
  const int l15 = lane & 15;
  const int g = lane >> 4;

  // routing flags for the 16 rows this lane will store (bf16 of 0.0/1.0 is exact)
  unsigned short flg[16];
  #pragma unroll
  for (int rt = 0; rt < 4; ++rt)
    #pragma unroll
    for (int r = 0; r < 4; ++r) {
      int row = rt * 16 + 4 * g + r;
      flg[rt * 4 + r] = *(const unsigned short*)((const char*)Xs +
                          ((row * 1024 + 1022) ^ ((row & 7) << 4)));
    }

  f32x4 keep[4][2];
  expert_pass<0>(Xs, Hs, pk,           pk + 196608, bt1, bt2, out, brow, lane, l15, g, w, flg, keep);
  expert_pass<1>(Xs, Hs, pk + 65536,   pk + 212992, ba1, ba2, out, brow, lane, l15, g, w, flg, keep);
  expert_pass<2>(Xs, Hs, pk + 131072,  pk + 229376, bv1, bv2, out + NTOK * 128, brow, lane, l15, g, w, flg, keep);
}

extern "C" void kernel_launch(void* const* d_in, const int* in_sizes, int n_in,
                              void* d_out, int out_size, void* d_ws, size_t ws_size,
                              hipStream_t stream) {
  const float* X   = (const float*)d_in[0];
  const float* Wt1 = (const float*)d_in[1];
  const float* bt1 = (const float*)d_in[2];
  const float* Wt2 = (const float*)d_in[3];
  const float* bt2 = (const float*)d_in[4];
  const float* Wa1 = (const float*)d_in[5];
  const float* ba1 = (const float*)d_in[6];
  const float* Wa2 = (const float*)d_in[7];
  const float* ba2 = (const float*)d_in[8];
  const float* Wv1 = (const float*)d_in[9];
  const float* bv1 = (const float*)d_in[10];
  const float* Wv2 = (const float*)d_in[11];
  const float* bv2 = (const float*)d_in[12];
  unsigned short* pk = (unsigned short*)d_ws;   // 245760 bf16 = 480 KiB packed weights

  pack_w<<<960, 256, 0, stream>>>(Wt1, Wa1, Wv1, Wt2, Wa2, Wv2, pk);
  mlp3<<<4096, 256, 0, stream>>>(X, pk, bt1, bt2, ba1, ba2, bv1, bv2, (float*)d_out);
}

// Round 2
// 271.673 us; speedup vs baseline: 1.0337x; 1.0337x over previous
//
#include <hip/hip_runtime.h>

#define NTOK 262144L

typedef __attribute__((ext_vector_type(4))) float f32x4;
typedef __attribute__((ext_vector_type(8))) short bf16x8;   // 8 x bf16 (4 VGPRs)

static __device__ __forceinline__ unsigned short f2bf(float f) {
  unsigned int u = __builtin_bit_cast(unsigned int, f);
  u += 0x7fffu + ((u >> 16) & 1u);          // round-nearest-even (inputs are normal)
  return (unsigned short)(u >> 16);
}

// ---- pre-pack all weights fp32 -> bf16 in MFMA B-fragment order ----
// W1 region: [e][kt=16][ct=8][lane=64][j=8]  (k = kt*32 + (lane>>4)*8 + j, col = ct*16 + (lane&15))
// W2 region: [e][kt=4 ][ct=8][lane=64][j=8]
__global__ void pack_w(const float* __restrict__ Wt1, const float* __restrict__ Wa1,
                       const float* __restrict__ Wv1, const float* __restrict__ Wt2,
                       const float* __restrict__ Wa2, const float* __restrict__ Wv2,
                       unsigned short* __restrict__ pk) {
  int idx = blockIdx.x * 256 + threadIdx.x;
  if (idx >= 245760) return;
  float v;
  if (idx < 196608) {
    int j = idx & 7, l = (idx >> 3) & 63, ct = (idx >> 9) & 7, kt = (idx >> 12) & 15, e = idx >> 16;
    const float* W = (e == 0) ? Wt1 : (e == 1) ? Wa1 : Wv1;
    v = W[(kt * 32 + ((l >> 4) * 8) + j) * 128 + ct * 16 + (l & 15)];
  } else {
    int i2 = idx - 196608;
    int j = i2 & 7, l = (i2 >> 3) & 63, ct = (i2 >> 9) & 7, kt = (i2 >> 12) & 3, e = i2 >> 14;
    const float* W = (e == 0) ? Wt2 : (e == 1) ? Wa2 : Wv2;
    v = W[(kt * 32 + ((l >> 4) * 8) + j) * 128 + ct * 16 + (l & 15)];
  }
  pk[idx] = f2bf(v);
}

// Xs swizzle: byte ^= (row&7)<<4           (reads/writes both 2-way max = free)
// Hs swizzle: byte ^= ((row&7)<<4)^((row&8)<<2)  (scalar u16 writes conflict-free)

__global__ __launch_bounds__(512, 4) void mlp3(
    const float* __restrict__ X, const unsigned short* __restrict__ pk,
    const float* __restrict__ bt1, const float* __restrict__ bt2,
    const float* __restrict__ ba1, const float* __restrict__ ba2,
    const float* __restrict__ bv1, const float* __restrict__ bv2,
    float* __restrict__ out) {
  __shared__ unsigned short Xs[2 * 64 * 128];   // 32 KiB: double-buffered 64x128 bf16 X chunk
  __shared__ unsigned short Hs[3 * 64 * 128];   // 48 KiB: hidden tiles for t,a,v
  const int t = threadIdx.x;
  const long brow = (long)blockIdx.x * 64;
  const int lane = t & 63;
  const int w = t >> 6;          // wave id 0..7 -> owns output cols w*16 .. w*16+15
  const int l15 = lane & 15;
  const int g = lane >> 4;

  const float4* __restrict__ Xv = (const float4*)(X + brow * 512);

  // ---- layer-1 accumulators for all 3 experts (fused K-loop) ----
  f32x4 at[4], aa[4], av[4];
  {
    float b0 = bt1[w * 16 + l15], b1v = ba1[w * 16 + l15], b2v = bv1[w * 16 + l15];
    #pragma unroll
    for (int rt = 0; rt < 4; ++rt) {
      at[rt] = (f32x4){b0, b0, b0, b0};
      aa[rt] = (f32x4){b1v, b1v, b1v, b1v};
      av[rt] = (f32x4){b2v, b2v, b2v, b2v};
    }
  }

  // ---- stage chunk 0 ----
  {
    float4 ld[4];
    #pragma unroll
    for (int i = 0; i < 4; ++i) {
      int f = t + 512 * i;
      ld[i] = Xv[(f >> 5) * 128 + (f & 31)];
    }
    #pragma unroll
    for (int i = 0; i < 4; ++i) {
      int f = t + 512 * i;
      int row = f >> 5, c4 = f & 31;
      unsigned long long p = (unsigned long long)f2bf(ld[i].x)
                           | ((unsigned long long)f2bf(ld[i].y) << 16)
                           | ((unsigned long long)f2bf(ld[i].z) << 32)
                           | ((unsigned long long)f2bf(ld[i].w) << 48);
      int addr = (row * 256 + c4 * 8) ^ ((row & 7) << 4);
      *(unsigned long long*)((char*)Xs + addr) = p;
    }
  }
  __syncthreads();

  unsigned fmask = 0;   // bit rt*4+r: flag != 0 for row rt*16+4g+r

  // ---- main K pipeline: 4 chunks of 128 ----
  #pragma unroll
  for (int kc = 0; kc < 4; ++kc) {
    float4 nx[4];
    if (kc < 3) {   // issue next chunk's global loads early (overlap with MFMA)
      #pragma unroll
      for (int i = 0; i < 4; ++i) {
        int f = t + 512 * i;
        nx[i] = Xv[(f >> 5) * 128 + (kc + 1) * 32 + (f & 31)];
      }
    }
    const char* xb = (const char*)Xs + (kc & 1) * 16384;
    #pragma unroll
    for (int ktl = 0; ktl < 4; ++ktl) {
      int kt = kc * 4 + ktl;
      int wo = ((kt * 8 + w) << 9) + (lane << 3);
      bf16x8 wt = *(const bf16x8*)(pk + wo);
      bf16x8 wa = *(const bf16x8*)(pk + 65536 + wo);
      bf16x8 wv = *(const bf16x8*)(pk + 131072 + wo);
      #pragma unroll
      for (int rt = 0; rt < 4; ++rt) {
        int row = rt * 16 + l15;
        bf16x8 a = *(const bf16x8*)(xb + ((row * 256 + ktl * 64 + g * 16) ^ ((row & 7) << 4)));
        at[rt] = __builtin_amdgcn_mfma_f32_16x16x32_bf16(a, wt, at[rt], 0, 0, 0);
        aa[rt] = __builtin_amdgcn_mfma_f32_16x16x32_bf16(a, wa, aa[rt], 0, 0, 0);
        av[rt] = __builtin_amdgcn_mfma_f32_16x16x32_bf16(a, wv, av[rt], 0, 0, 0);
      }
    }
    if (kc == 3) {
      // routing flags: global col 511 = chunk-3 local col 127 (byte 254), buf1
      #pragma unroll
      for (int rt = 0; rt < 4; ++rt)
        #pragma unroll
        for (int r = 0; r < 4; ++r) {
          int row = rt * 16 + 4 * g + r;
          unsigned short fv = *(const unsigned short*)((const char*)Xs + 16384 +
                               ((row * 256 + 254) ^ ((row & 7) << 4)));
          if (fv != 0) fmask |= 1u << (rt * 4 + r);
        }
    }
    if (kc < 3) {
      #pragma unroll
      for (int i = 0; i < 4; ++i) {
        int f = t + 512 * i;
        int row = f >> 5, c4 = f & 31;
        unsigned long long p = (unsigned long long)f2bf(nx[i].x)
                             | ((unsigned long long)f2bf(nx[i].y) << 16)
                             | ((unsigned long long)f2bf(nx[i].z) << 32)
                             | ((unsigned long long)f2bf(nx[i].w) << 48);
        int addr = ((kc + 1) & 1) * 16384 + ((row * 256 + c4 * 8) ^ ((row & 7) << 4));
        *(unsigned long long*)((char*)Xs + addr) = p;
      }
      __syncthreads();
    }
  }

  // ---- relu + write the 3 hidden tiles (Hs disjoint from Xs: no barrier needed) ----
  #pragma unroll
  for (int rt = 0; rt < 4; ++rt)
    #pragma unroll
    for (int r = 0; r < 4; ++r) {
      int row = rt * 16 + 4 * g + r;
      int col = w * 16 + l15;
      int ha = (row * 256 + col * 2) ^ ((row & 7) << 4) ^ ((row & 8) << 2);
      *(unsigned short*)((char*)Hs + ha)         = f2bf(fmaxf(at[rt][r], 0.f));
      *(unsigned short*)((char*)Hs + 16384 + ha) = f2bf(fmaxf(aa[rt][r], 0.f));
      *(unsigned short*)((char*)Hs + 32768 + ha) = f2bf(fmaxf(av[rt][r], 0.f));
    }
  __syncthreads();

  // ---- layer 2 for one expert: a2 = relu(H_e) @ W2_e + b2_e ----
  auto layer2 = [&](int e, const float* __restrict__ b2, f32x4 a2[4]) {
    float bv = b2[w * 16 + l15];
    #pragma unroll
    for (int rt = 0; rt < 4; ++rt) a2[rt] = (f32x4){bv, bv, bv, bv};
    const unsigned short* W2f = pk + 196608 + e * 16384;
    const char* hb = (const char*)Hs + e * 16384;
    #pragma unroll
    for (int kt = 0; kt < 4; ++kt) {
      bf16x8 wb = *(const bf16x8*)(W2f + ((kt * 8 + w) << 9) + (lane << 3));
      #pragma unroll
      for (int rt = 0; rt < 4; ++rt) {
        int row = rt * 16 + l15;
        bf16x8 a = *(const bf16x8*)(hb + ((row * 256 + kt * 64 + g * 16)
                      ^ ((row & 7) << 4) ^ ((row & 8) << 2)));
        a2[rt] = __builtin_amdgcn_mfma_f32_16x16x32_bf16(a, wb, a2[rt], 0, 0, 0);
      }
    }
  };

  f32x4 keep[4], a2[4];
  layer2(0, bt2, keep);    // transform expert result stays in registers
  layer2(1, ba2, a2);      // actor expert
  {
    const int col = w * 16 + l15;
    #pragma unroll
    for (int rt = 0; rt < 4; ++rt)
      #pragma unroll
      for (int r = 0; r < 4; ++r) {
        long row = brow + rt * 16 + 4 * g + r;
        float sel = ((fmask >> (rt * 4 + r)) & 1u) ? a2[rt][r] : keep[rt][r];
        out[row * 128 + col] = sel;
      }
  }
  layer2(2, bv2, a2);      // value head
  {
    const int col = w * 16 + l15;
    float* __restrict__ ov = out + NTOK * 128;
    #pragma unroll
    for (int rt = 0; rt < 4; ++rt)
      #pragma unroll
      for (int r = 0; r < 4; ++r) {
        long row = brow + rt * 16 + 4 * g + r;
        ov[row * 128 + col] = fmaxf(a2[rt][r], 0.f);
      }
  }
}

extern "C" void kernel_launch(void* const* d_in, const int* in_sizes, int n_in,
                              void* d_out, int out_size, void* d_ws, size_t ws_size,
                              hipStream_t stream) {
  const float* X   = (const float*)d_in[0];
  const float* Wt1 = (const float*)d_in[1];
  const float* bt1 = (const float*)d_in[2];
  const float* Wt2 = (const float*)d_in[3];
  const float* bt2 = (const float*)d_in[4];
  const float* Wa1 = (const float*)d_in[5];
  const float* ba1 = (const float*)d_in[6];
  const float* Wa2 = (const float*)d_in[7];
  const float* ba2 = (const float*)d_in[8];
  const float* Wv1 = (const float*)d_in[9];
  const float* bv1 = (const float*)d_in[10];
  const float* Wv2 = (const float*)d_in[11];
  const float* bv2 = (const float*)d_in[12];
  unsigned short* pk = (unsigned short*)d_ws;   // 245760 bf16 = 480 KiB packed weights

  pack_w<<<960, 256, 0, stream>>>(Wt1, Wa1, Wv1, Wt2, Wa2, Wv2, pk);
  mlp3<<<4096, 512, 0, stream>>>(X, pk, bt1, bt2, ba1, ba2, bv1, bv2, (float*)d_out);
}